// Round 14
// baseline (615.593 us; speedup 1.0000x reference)
//
#include <hip/hip_runtime.h>
#include <stdint.h>

#define NFIELD 20
#define HID 1024
#define KEXP 16
#define KX 1280   // nfield * data_nemb
#define KS 320    // nfield * sql_nemb
#define BATCH 8192

typedef __bf16 bf16x8 __attribute__((ext_vector_type(8)));
typedef float f32x4 __attribute__((ext_vector_type(4)));
typedef float f32x16 __attribute__((ext_vector_type(16)));

__device__ __forceinline__ unsigned short f2bf(float f) {
  union { float f; unsigned u; } v; v.f = f;
  unsigned r = v.u + 0x7FFFu + ((v.u >> 16) & 1u);  // RNE
  return (unsigned short)(r >> 16);
}

__device__ __forceinline__ void gload16(const void* g, void* l) {
  __builtin_amdgcn_global_load_lds(
      (const __attribute__((address_space(1))) unsigned int*)(uintptr_t)g,
      (__attribute__((address_space(3))) unsigned int*)(unsigned)(uintptr_t)l,
      16, 0, 0);
}

#define SBAR() asm volatile("s_barrier" ::: "memory")

// ---------------- prep kernels ----------------

__global__ void transpose_cvt(const float* __restrict__ src, unsigned short* __restrict__ dst,
                              int R, int C, long sstride, long dstride) {
  __shared__ float tile[32][33];
  const float* s = src + (size_t)blockIdx.z * sstride;
  unsigned short* d = dst + (size_t)blockIdx.z * dstride;
  const int r0 = blockIdx.y * 32, c0 = blockIdx.x * 32;
  const int tx = threadIdx.x & 31, ty = threadIdx.x >> 5;
#pragma unroll
  for (int i = 0; i < 4; ++i)
    tile[ty + 8 * i][tx] = s[(size_t)(r0 + ty + 8 * i) * C + c0 + tx];
  __syncthreads();
#pragma unroll
  for (int i = 0; i < 4; ++i)
    d[(size_t)(c0 + ty + 8 * i) * R + r0 + tx] = f2bf(tile[tx][ty + 8 * i]);
}

__global__ void gather_x_k(const int* __restrict__ x, const float* __restrict__ tab,
                           unsigned short* __restrict__ out) {
  const int b = blockIdx.x;
  const int f = threadIdx.x >> 4;
  const int q = threadIdx.x & 15;
  const int idx = x[b * NFIELD + f];
  const float4 v = *(const float4*)(tab + (size_t)idx * 64 + q * 4);
  ushort4 o;
  o.x = f2bf(v.x); o.y = f2bf(v.y); o.z = f2bf(v.z); o.w = f2bf(v.w);
  *(ushort4*)(out + (size_t)b * KX + f * 64 + q * 4) = o;
}

__global__ void gather_sql_k(const int* __restrict__ sql, const float* __restrict__ tab,
                             unsigned short* __restrict__ out) {
  const int t = blockIdx.x * 256 + threadIdx.x;
  const int b = t / 80;
  const int r = t - b * 80;
  const int f = r >> 2, q = r & 3;
  const int idx = sql[b * NFIELD + f];
  const float4 v = *(const float4*)(tab + (size_t)idx * 16 + q * 4);
  ushort4 o;
  o.x = f2bf(v.x); o.y = f2bf(v.y); o.z = f2bf(v.z); o.w = f2bf(v.w);
  *(ushort4*)(out + (size_t)b * KS + f * 16 + q * 4) = o;
}

// ---------------- 128x128 / BK=64 GEMM, 32x32x16 MFMA (main experts) ----------------
// R12 frag-pipelined structure, MFMA shape switched 16x16x32 -> 32x32x16:
// half the MFMA instructions, ~17% less matrix-pipe time (8.07 vs 2*4.85 cyc per 32k FLOP).
// Per wave 64x64 = 2x2 tiles of 32x32; frags: lane l holds X[l&31][(l>>5)*8+j] per k16 chunk.
// C/D (m74/m101-verified): col = lane&31, row = (reg&3) + 8*(reg>>2) + 4*(lane>>5).
// BODY(T): {MM8 c16{0,1}(CUR); lgkm0; vmcnt0; SBAR; stage(T+2); readfr(T+1->NXT); MM8 c16{2,3}(CUR); SBAR}
template <int KTOT>
__global__ __launch_bounds__(256, 2) void gemm32(const __bf16* __restrict__ A,
                                                 const __bf16* __restrict__ Bt,
                                                 const float* __restrict__ bias,
                                                 const float* __restrict__ W2,
                                                 float* __restrict__ out) {
  constexpr int NT = KTOT / 64;
  static_assert(NT >= 3, "pipeline needs NT>=3");
  alignas(16) __shared__ __bf16 As[2][128][64];
  alignas(16) __shared__ __bf16 Bs[2][128][64];

  const int tid = threadIdx.x;
  const int lane = tid & 63;
  const int wave = tid >> 6;        // 0..3
  const int wr = wave >> 1;         // 0..1 : M half (64 rows)
  const int wc = wave & 1;          // 0..1 : N half (64 cols)

  // L2-aware 2-level swizzle: XCD chunk + 8-wide n-groups, m-major within chunk.
  const unsigned f = blockIdx.y * gridDim.x + blockIdx.x;
  const unsigned nwg = gridDim.x * gridDim.y;
  const unsigned s = (f >> 3) + (f & 7u) * (nwg >> 3);
  const int m0 = (int)((s & 511u) >> 3) * 128;
  const int n0 = (int)((s >> 9) * 8 + (s & 7u)) * 128;

  // staging map: gload j covers 8 rows; lane l -> row j*8 + l/8, global chunk (l&7)^(l/8)
  // => LDS[r][p] holds global chunk p^(r&7)  (both-sides swizzle, linear LDS dest)
  const int srow = lane >> 3;
  const int sch = (lane & 7) ^ srow;
  const int l31 = lane & 31, g5 = lane >> 5;

  const __bf16* Ag = A + (size_t)(m0 + wave * 32 + srow) * KTOT + sch * 8;
  const __bf16* Bg = Bt + (size_t)(n0 + wave * 32 + srow) * KTOT + sch * 8;

  auto stage = [&](int t) {
    const int c = t & 1;
#pragma unroll
    for (int j = 0; j < 4; ++j)
      gload16(Ag + (size_t)(j * 8) * KTOT + t * 64, (void*)&As[c][wave * 32 + j * 8][0]);
#pragma unroll
    for (int j = 0; j < 4; ++j)
      gload16(Bg + (size_t)(j * 8) * KTOT + t * 64, (void*)&Bs[c][wave * 32 + j * 8][0]);
  };
  // frags for 32x32x16: per k16 chunk q (0..3), 16B at K-chunk (q*2+g5), row wr*64+mi*32+l31
  auto readfr = [&](int c, bf16x8 (&af)[2][4], bf16x8 (&bfr)[2][4]) {
#pragma unroll
    for (int mi = 0; mi < 2; ++mi) {
      const int row = wr * 64 + mi * 32 + l31;
#pragma unroll
      for (int q = 0; q < 4; ++q)
        af[mi][q] = *(const bf16x8*)&As[c][row][((q * 2 + g5) ^ (row & 7)) * 8];
    }
#pragma unroll
    for (int ni = 0; ni < 2; ++ni) {
      const int row = wc * 64 + ni * 32 + l31;
#pragma unroll
      for (int q = 0; q < 4; ++q)
        bfr[ni][q] = *(const bf16x8*)&Bs[c][row][((q * 2 + g5) ^ (row & 7)) * 8];
    }
  };

  f32x16 acc[2][2] = {};
  bf16x8 afA[2][4], bfA[2][4], afB[2][4], bfB[2][4];

#define MM8(AF, BF, C0)                                                        \
  __builtin_amdgcn_s_setprio(1);                                               \
  _Pragma("unroll") for (int mi = 0; mi < 2; ++mi)                             \
  _Pragma("unroll") for (int ni = 0; ni < 2; ++ni)                             \
  _Pragma("unroll") for (int c = 0; c < 2; ++c)                                \
      acc[mi][ni] = __builtin_amdgcn_mfma_f32_32x32x16_bf16(                   \
          AF[mi][(C0) + c], BF[ni][(C0) + c], acc[mi][ni], 0, 0, 0);           \
  __builtin_amdgcn_s_setprio(0);

#define BODY(T, AFC, BFC, AFN, BFN)                                            \
  MM8(AFC, BFC, 0);                                                            \
  asm volatile("s_waitcnt lgkmcnt(0)" ::: "memory");                           \
  asm volatile("s_waitcnt vmcnt(0)" ::: "memory");                             \
  SBAR();                                                                      \
  if ((T) + 2 < NT) stage((T) + 2);                                            \
  readfr(((T) + 1) & 1, AFN, BFN);                                             \
  MM8(AFC, BFC, 2);                                                            \
  SBAR();

  // prologue: stage tiles 0,1; all-wave drain; prefetch frags(0)
  stage(0);
  stage(1);
  asm volatile("s_waitcnt vmcnt(0)" ::: "memory");
  SBAR();
  readfr(0, afA, bfA);

  int t = 0;
  for (; t + 1 < NT - 1; t += 2) {
    BODY(t, afA, bfA, afB, bfB);
    BODY(t + 1, afB, bfB, afA, bfA);
  }
  if constexpr (((NT - 1) & 1) != 0) {
    BODY(NT - 2, afA, bfA, afB, bfB);
    MM8(afB, bfB, 0);
    MM8(afB, bfB, 2);
  } else {
    MM8(afA, bfA, 0);
    MM8(afA, bfA, 2);
  }
#undef BODY
#undef MM8

  // epilogue: relu(acc+bias) dot eW2, reduce over 32-lane column groups, atomic accumulate
  int ncol[2];
  float bsv[2], w2v[2];
#pragma unroll
  for (int ni = 0; ni < 2; ++ni) {
    ncol[ni] = n0 + wc * 64 + ni * 32 + l31;   // C/D: col = lane&31
    bsv[ni] = bias[ncol[ni]];
    w2v[ni] = W2[ncol[ni]];
  }
  const int oc = n0 >> 10;
#pragma unroll
  for (int mi = 0; mi < 2; ++mi)
#pragma unroll
    for (int r = 0; r < 16; ++r) {
      float a0 = acc[mi][0][r] + bsv[0]; a0 = a0 > 0.f ? a0 : 0.f;
      float a1 = acc[mi][1][r] + bsv[1]; a1 = a1 > 0.f ? a1 : 0.f;
      float s2 = a0 * w2v[0] + a1 * w2v[1];
      s2 += __shfl_xor(s2, 1);
      s2 += __shfl_xor(s2, 2);
      s2 += __shfl_xor(s2, 4);
      s2 += __shfl_xor(s2, 8);
      s2 += __shfl_xor(s2, 16);
      if (l31 == 0) {
        const int row = m0 + wr * 64 + mi * 32 + (r & 3) + 8 * (r >> 2) + 4 * g5;
        atomicAdd(&out[row * KEXP + oc], s2);
      }
    }
}

// ---------------- 128x128 / BK=64 fragment-pipelined GEMM (gate, NJO=16) — R12-proven ----
template <int NJO, int KTOT>
__global__ __launch_bounds__(256, 2) void gemm_k(const __bf16* __restrict__ A,
                                                 const __bf16* __restrict__ Bt,
                                                 const float* __restrict__ bias,
                                                 const float* __restrict__ W2,
                                                 float* __restrict__ out) {
  constexpr int NT = KTOT / 64;
  static_assert(NT >= 3, "pipeline needs NT>=3");
  alignas(16) __shared__ __bf16 As[2][128][64];
  alignas(16) __shared__ __bf16 Bs[2][128][64];

  const int tid = threadIdx.x;
  const int lane = tid & 63;
  const int wave = tid >> 6;
  const int wr = wave >> 1, wc = wave & 1;

  const unsigned f = blockIdx.y * gridDim.x + blockIdx.x;
  const unsigned nwg = gridDim.x * gridDim.y;
  const unsigned s = (f >> 3) + (f & 7u) * (nwg >> 3);
  const int m0 = (int)((s & 511u) >> 3) * 128;
  const int n0 = (int)((s >> 9) * 8 + (s & 7u)) * 128;

  const int srow = lane >> 3;
  const int sch = (lane & 7) ^ srow;
  const int r15 = lane & 15, g4 = lane >> 4;

  const __bf16* Ag = A + (size_t)(m0 + wave * 32 + srow) * KTOT + sch * 8;
  const __bf16* Bg = Bt + (size_t)(n0 + wave * 32 + srow) * KTOT + sch * 8;

  auto stage = [&](int t) {
    const int c = t & 1;
#pragma unroll
    for (int j = 0; j < 4; ++j)
      gload16(Ag + (size_t)(j * 8) * KTOT + t * 64, (void*)&As[c][wave * 32 + j * 8][0]);
#pragma unroll
    for (int j = 0; j < 4; ++j)
      gload16(Bg + (size_t)(j * 8) * KTOT + t * 64, (void*)&Bs[c][wave * 32 + j * 8][0]);
  };
  auto readfr = [&](int c, bf16x8 (&af)[4][2], bf16x8 (&bfr)[4][2]) {
#pragma unroll
    for (int mi = 0; mi < 4; ++mi) {
      const int row = wr * 64 + mi * 16 + r15;
#pragma unroll
      for (int kk = 0; kk < 2; ++kk)
        af[mi][kk] = *(const bf16x8*)&As[c][row][((kk * 4 + g4) ^ (row & 7)) * 8];
    }
#pragma unroll
    for (int ni = 0; ni < 4; ++ni) {
      const int row = wc * 64 + ni * 16 + r15;
#pragma unroll
      for (int kk = 0; kk < 2; ++kk)
        bfr[ni][kk] = *(const bf16x8*)&Bs[c][row][((kk * 4 + g4) ^ (row & 7)) * 8];
    }
  };

  f32x4 acc[4][4] = {};
  bf16x8 afA[4][2], bfA[4][2], afB[4][2], bfB[4][2];

#define MFMA16(AF, BF, KK)                                                     \
  __builtin_amdgcn_s_setprio(1);                                               \
  _Pragma("unroll") for (int mi = 0; mi < 4; ++mi)                             \
  _Pragma("unroll") for (int ni = 0; ni < 4; ++ni)                             \
      acc[mi][ni] = __builtin_amdgcn_mfma_f32_16x16x32_bf16(                   \
          AF[mi][KK], BF[ni][KK], acc[mi][ni], 0, 0, 0);                       \
  __builtin_amdgcn_s_setprio(0);

#define BODY(T, AFC, BFC, AFN, BFN)                                            \
  MFMA16(AFC, BFC, 0);                                                         \
  asm volatile("s_waitcnt lgkmcnt(0)" ::: "memory");                           \
  asm volatile("s_waitcnt vmcnt(0)" ::: "memory");                             \
  SBAR();                                                                      \
  if ((T) + 2 < NT) stage((T) + 2);                                            \
  readfr(((T) + 1) & 1, AFN, BFN);                                             \
  MFMA16(AFC, BFC, 1);                                                         \
  SBAR();

  stage(0);
  stage(1);
  asm volatile("s_waitcnt vmcnt(0)" ::: "memory");
  SBAR();
  readfr(0, afA, bfA);

  int t = 0;
  for (; t + 1 < NT - 1; t += 2) {
    BODY(t, afA, bfA, afB, bfB);
    BODY(t + 1, afB, bfB, afA, bfA);
  }
  if constexpr (((NT - 1) & 1) != 0) {
    BODY(NT - 2, afA, bfA, afB, bfB);
    MFMA16(afB, bfB, 0);
    MFMA16(afB, bfB, 1);
  } else {
    MFMA16(afA, bfA, 0);
    MFMA16(afA, bfA, 1);
  }
#undef BODY
#undef MFMA16

  int ncol[4];
  float bsv[4];
#pragma unroll
  for (int ni = 0; ni < 4; ++ni) {
    ncol[ni] = n0 + wc * 64 + ni * 16 + r15;
    bsv[ni] = bias[ncol[ni]];
  }
#pragma unroll
  for (int mi = 0; mi < 4; ++mi)
#pragma unroll
    for (int ni = 0; ni < 4; ++ni)
#pragma unroll
      for (int j = 0; j < 4; ++j) {
        float v = acc[mi][ni][j] + bsv[ni];
        acc[mi][ni][j] = v > 0.f ? v : 0.f;
      }
#pragma unroll
  for (int jo = 0; jo < NJO; ++jo) {
    float w4[4];
#pragma unroll
    for (int ni = 0; ni < 4; ++ni)
      w4[ni] = (NJO == 1) ? W2[ncol[ni]] : W2[ncol[ni] * NJO + jo];
#pragma unroll
    for (int mi = 0; mi < 4; ++mi)
#pragma unroll
      for (int j = 0; j < 4; ++j) {
        float s2 = acc[mi][0][j] * w4[0] + acc[mi][1][j] * w4[1] +
                   acc[mi][2][j] * w4[2] + acc[mi][3][j] * w4[3];
        s2 += __shfl_xor(s2, 1);
        s2 += __shfl_xor(s2, 2);
        s2 += __shfl_xor(s2, 4);
        s2 += __shfl_xor(s2, 8);
        if (r15 == 0) {
          const int row = m0 + wr * 64 + mi * 16 + g4 * 4 + j;
          const int oc = (NJO == 1) ? (n0 >> 10) : jo;
          atomicAdd(&out[row * KEXP + oc], s2);
        }
      }
  }
}

// ---------------- entmax (alpha=1.5, 50 bisect iters) + combine + gate colsums ------------
__global__ void entmax_combine(const float* __restrict__ gacc, const float* __restrict__ gb2,
                               const float* __restrict__ yk, const float* __restrict__ eb2,
                               float* __restrict__ y, double* __restrict__ colsum) {
  const int b = blockIdx.x * 256 + threadIdx.x;
  float x[16];
  float mx = -3.4e38f;
#pragma unroll
  for (int j = 0; j < 16; ++j) {
    x[j] = (gacc[b * 16 + j] + gb2[j]) * 0.5f;  // * (alpha-1)
    mx = fmaxf(mx, x[j]);
  }
  float lo = mx - 1.0f, hi = mx - 0.25f;  // d^(1-alpha) = 16^-0.5
  float flo = -1.0f;
#pragma unroll
  for (int j = 0; j < 16; ++j) {
    float d = x[j] - lo; d = d > 0.f ? d : 0.f;
    flo += d * d;
  }
  for (int it = 0; it < 50; ++it) {
    const float tm = 0.5f * (lo + hi);
    float fm = -1.0f;
#pragma unroll
    for (int j = 0; j < 16; ++j) {
      float d = x[j] - tm; d = d > 0.f ? d : 0.f;
      fm += d * d;
    }
    if (fm * flo >= 0.f) { lo = tm; flo = fm; } else { hi = tm; }
  }
  const float tm = 0.5f * (lo + hi);
  float p[16], ps = 0.f;
#pragma unroll
  for (int j = 0; j < 16; ++j) {
    float d = x[j] - tm; d = d > 0.f ? d : 0.f;
    p[j] = d * d; ps += p[j];
  }
  const float inv = 1.0f / ps;
  float yv = 0.f;
#pragma unroll
  for (int j = 0; j < 16; ++j) {
    p[j] *= inv;
    yv += p[j] * (yk[b * 16 + j] + eb2[j]);
  }
  y[b] = yv;

  const int lane = threadIdx.x & 63, wv = threadIdx.x >> 6;
  __shared__ float red[4][16];
#pragma unroll
  for (int j = 0; j < 16; ++j) {
    float v = p[j];
    v += __shfl_xor(v, 1);  v += __shfl_xor(v, 2);  v += __shfl_xor(v, 4);
    v += __shfl_xor(v, 8);  v += __shfl_xor(v, 16); v += __shfl_xor(v, 32);
    if (lane == 0) red[wv][j] = v;
  }
  __syncthreads();
  if (threadIdx.x < 16) {
    double s = (double)red[0][threadIdx.x] + (double)red[1][threadIdx.x] +
               (double)red[2][threadIdx.x] + (double)red[3][threadIdx.x];
    atomicAdd(&colsum[threadIdx.x], s);
  }
}

__global__ void loss_k(const double* __restrict__ colsum, float* __restrict__ out) {
  if (threadIdx.x == 0 && blockIdx.x == 0) {
    double m = 0.0;
    for (int k = 0; k < 16; ++k) m += colsum[k];
    m *= (1.0 / 16.0);
    double var = 0.0;
    for (int k = 0; k < 16; ++k) { const double d = colsum[k] - m; var += d * d; }
    var *= (1.0 / 15.0);  // ddof=1
    out[0] = (float)(var / (m * m + 1e-10));
  }
}

// ---------------- launch ----------------
extern "C" void kernel_launch(void* const* d_in, const int* in_sizes, int n_in,
                              void* d_out, int out_size, void* d_ws, size_t ws_size,
                              hipStream_t stream) {
  const int*   x    = (const int*)d_in[0];
  const int*   sql  = (const int*)d_in[1];
  const float* sqlT = (const float*)d_in[2];
  const float* inT  = (const float*)d_in[3];
  const float* gW1  = (const float*)d_in[4];
  const float* gb1  = (const float*)d_in[5];
  const float* gW2  = (const float*)d_in[6];
  const float* gb2  = (const float*)d_in[7];
  const float* eW1  = (const float*)d_in[8];
  const float* eb1  = (const float*)d_in[9];
  const float* eW2  = (const float*)d_in[10];
  const float* eb2  = (const float*)d_in[11];

  char* ws = (char*)d_ws;
  unsigned short* eW1T = (unsigned short*)(ws);              // [16384][1280] bf16
  unsigned short* xemb = (unsigned short*)(ws + 41943040);   // [8192][1280]
  unsigned short* semb = (unsigned short*)(ws + 62914560);   // [8192][320]
  unsigned short* gW1T = (unsigned short*)(ws + 68157440);   // [1024][320]
  float*  yk     = (float*)(ws + 68812800);                  // [8192][16]
  float*  gacc   = (float*)(ws + 69337088);                  // [8192][16]
  double* colsum = (double*)(ws + 69861376);                 // [16]

  hipMemsetAsync(yk, 0, 524288 * 2 + 128, stream);

  transpose_cvt<<<dim3(32, 40, 16), 256, 0, stream>>>(eW1, eW1T, 1280, 1024, 1280L * 1024, 1024L * 1280);
  transpose_cvt<<<dim3(32, 10, 1), 256, 0, stream>>>(gW1, gW1T, 320, 1024, 0, 0);
  gather_x_k<<<BATCH, 320, 0, stream>>>(x, inT, xemb);
  gather_sql_k<<<BATCH * 80 / 256, 256, 0, stream>>>(sql, sqlT, semb);

  gemm32<KX><<<dim3(16384 / 128, BATCH / 128), 256, 0, stream>>>(
      (const __bf16*)xemb, (const __bf16*)eW1T, eb1, eW2, yk);
  gemm_k<16, KS><<<dim3(HID / 128, BATCH / 128), 256, 0, stream>>>(
      (const __bf16*)semb, (const __bf16*)gW1T, gb1, gW2, gacc);

  entmax_combine<<<BATCH / 256, 256, 0, stream>>>(gacc, gb2, yk, eb2, (float*)d_out, colsum);
  loss_k<<<1, 64, 0, stream>>>(colsum, (float*)d_out + BATCH);
}

// Round 15
// 555.985 us; speedup vs baseline: 1.1072x; 1.1072x over previous
//
#include <hip/hip_runtime.h>
#include <stdint.h>

#define NFIELD 20
#define HID 1024
#define KEXP 16
#define KX 1280   // nfield * data_nemb
#define KS 320    // nfield * sql_nemb
#define BATCH 8192

typedef __bf16 bf16x8 __attribute__((ext_vector_type(8)));
typedef float f32x4 __attribute__((ext_vector_type(4)));

__device__ __forceinline__ unsigned short f2bf(float f) {
  union { float f; unsigned u; } v; v.f = f;
  unsigned r = v.u + 0x7FFFu + ((v.u >> 16) & 1u);  // RNE
  return (unsigned short)(r >> 16);
}

__device__ __forceinline__ void gload16(const void* g, void* l) {
  __builtin_amdgcn_global_load_lds(
      (const __attribute__((address_space(1))) unsigned int*)(uintptr_t)g,
      (__attribute__((address_space(3))) unsigned int*)(unsigned)(uintptr_t)l,
      16, 0, 0);
}

#define SBAR() asm volatile("s_barrier" ::: "memory")

// ---------------- prep kernels ----------------

__global__ void transpose_cvt(const float* __restrict__ src, unsigned short* __restrict__ dst,
                              int R, int C, long sstride, long dstride) {
  __shared__ float tile[32][33];
  const float* s = src + (size_t)blockIdx.z * sstride;
  unsigned short* d = dst + (size_t)blockIdx.z * dstride;
  const int r0 = blockIdx.y * 32, c0 = blockIdx.x * 32;
  const int tx = threadIdx.x & 31, ty = threadIdx.x >> 5;
#pragma unroll
  for (int i = 0; i < 4; ++i)
    tile[ty + 8 * i][tx] = s[(size_t)(r0 + ty + 8 * i) * C + c0 + tx];
  __syncthreads();
#pragma unroll
  for (int i = 0; i < 4; ++i)
    d[(size_t)(c0 + ty + 8 * i) * R + r0 + tx] = f2bf(tile[tx][ty + 8 * i]);
}

__global__ void gather_x_k(const int* __restrict__ x, const float* __restrict__ tab,
                           unsigned short* __restrict__ out) {
  const int b = blockIdx.x;
  const int f = threadIdx.x >> 4;
  const int q = threadIdx.x & 15;
  const int idx = x[b * NFIELD + f];
  const float4 v = *(const float4*)(tab + (size_t)idx * 64 + q * 4);
  ushort4 o;
  o.x = f2bf(v.x); o.y = f2bf(v.y); o.z = f2bf(v.z); o.w = f2bf(v.w);
  *(ushort4*)(out + (size_t)b * KX + f * 64 + q * 4) = o;
}

__global__ void gather_sql_k(const int* __restrict__ sql, const float* __restrict__ tab,
                             unsigned short* __restrict__ out) {
  const int t = blockIdx.x * 256 + threadIdx.x;
  const int b = t / 80;
  const int r = t - b * 80;
  const int f = r >> 2, q = r & 3;
  const int idx = sql[b * NFIELD + f];
  const float4 v = *(const float4*)(tab + (size_t)idx * 16 + q * 4);
  ushort4 o;
  o.x = f2bf(v.x); o.y = f2bf(v.y); o.z = f2bf(v.z); o.w = f2bf(v.w);
  *(ushort4*)(out + (size_t)b * KS + f * 16 + q * 4) = o;
}

// ---------------- 128x128 / BK=32, 4-buffer, 2-tile super-body GEMM ----------------
// C = A[M,K]*Bt[N,K]^T; epilogue relu(acc+bias) dot W2 -> atomic out.
// 4 waves (2x2), 64x64/wave, LDS = 4 bufs x (128x32 A + 128x32 B) = 64 KiB -> 2 blocks/CU.
// Super-body k (tiles 2k,2k+1): {MM16(tile2k,fragsA); MM16(tile2k+1,fragsB);
//   lgkm0; vmcnt0; SBAR; stage(2k+4),stage(2k+5); readfr(2k+2->A), readfr(2k+3->B)}
// ONE barrier per 2 tiles. Stage->drain distance = 1 full super-body (~1200cyc > 900 HBM miss).
// Cross-wave: lgkm0 before SBAR retires every wave's readfr(2k/2k+1) before buf overwrite;
// vmcnt0 before SBAR retires every wave's stage(2k+2/2k+3) before any wave reads them.
// BK=32 swizzle: LDS[r][p] holds global chunk p ^ ((r>>1)&3); frag read chunk g4^((row>>1)&3)
// -> banks (row%2)*16 + ch*4: 2-way aliasing only (free, m136).
template <int NJO, int KTOT>
__global__ __launch_bounds__(256, 2) void gemm_q(const __bf16* __restrict__ A,
                                                 const __bf16* __restrict__ Bt,
                                                 const float* __restrict__ bias,
                                                 const float* __restrict__ W2,
                                                 float* __restrict__ out) {
  constexpr int NT = KTOT / 32;
  static_assert(NT % 2 == 0 && NT >= 4, "even NT >= 4");
  alignas(16) __shared__ __bf16 As[4][128][32];
  alignas(16) __shared__ __bf16 Bs[4][128][32];

  const int tid = threadIdx.x;
  const int lane = tid & 63;
  const int wave = tid >> 6;        // 0..3
  const int wr = wave >> 1;         // 0..1 : M half (64 rows)
  const int wc = wave & 1;          // 0..1 : N half (64 cols)

  // L2-aware 2-level swizzle: XCD chunk + 8-wide n-groups, m-major within chunk.
  const unsigned f = blockIdx.y * gridDim.x + blockIdx.x;
  const unsigned nwg = gridDim.x * gridDim.y;
  const unsigned s = (f >> 3) + (f & 7u) * (nwg >> 3);
  const int m0 = (int)((s & 511u) >> 3) * 128;
  const int n0 = (int)((s >> 9) * 8 + (s & 7u)) * 128;

  // staging: gload covers 16 rows (1KB); lane l -> row l>>2, pos l&3,
  // global chunk (l&3) ^ ((srow>>1)&3)  => LDS[r][p] = global chunk p ^ ((r>>1)&3)
  const int srow = lane >> 2;
  const int sch = (lane & 3) ^ ((srow >> 1) & 3);
  const int r15 = lane & 15, g4 = lane >> 4;

  const __bf16* Ag = A + (size_t)(m0 + wave * 32 + srow) * KTOT + sch * 8;
  const __bf16* Bg = Bt + (size_t)(n0 + wave * 32 + srow) * KTOT + sch * 8;

  auto stage = [&](int t) {  // 2 A + 2 B gload16 per wave
    const int c = t & 3;
#pragma unroll
    for (int j = 0; j < 2; ++j)
      gload16(Ag + (size_t)(j * 16) * KTOT + t * 32, (void*)&As[c][wave * 32 + j * 16][0]);
#pragma unroll
    for (int j = 0; j < 2; ++j)
      gload16(Bg + (size_t)(j * 16) * KTOT + t * 32, (void*)&Bs[c][wave * 32 + j * 16][0]);
  };
  auto readfr = [&](int t, bf16x8 (&af)[4], bf16x8 (&bfr)[4]) {
    const int c = t & 3;
#pragma unroll
    for (int mi = 0; mi < 4; ++mi) {
      const int row = wr * 64 + mi * 16 + r15;
      af[mi] = *(const bf16x8*)&As[c][row][((g4 ^ ((row >> 1) & 3))) * 8];
    }
#pragma unroll
    for (int ni = 0; ni < 4; ++ni) {
      const int row = wc * 64 + ni * 16 + r15;
      bfr[ni] = *(const bf16x8*)&Bs[c][row][((g4 ^ ((row >> 1) & 3))) * 8];
    }
  };

  f32x4 acc[4][4] = {};
  bf16x8 afA[4], bfA[4], afB[4], bfB[4];

#define MM16(AF, BF)                                                           \
  __builtin_amdgcn_s_setprio(1);                                               \
  _Pragma("unroll") for (int mi = 0; mi < 4; ++mi)                             \
  _Pragma("unroll") for (int ni = 0; ni < 4; ++ni)                             \
      acc[mi][ni] = __builtin_amdgcn_mfma_f32_16x16x32_bf16(                   \
          AF[mi], BF[ni], acc[mi][ni], 0, 0, 0);                               \
  __builtin_amdgcn_s_setprio(0);

  // prologue: stage tiles 0..3; drain; prefetch frags for tiles 0,1
  stage(0); stage(1); stage(2); stage(3);
  asm volatile("s_waitcnt vmcnt(0)" ::: "memory");
  SBAR();
  readfr(0, afA, bfA);
  readfr(1, afB, bfB);

  for (int k = 0; k < NT / 2; ++k) {
    // compiler inserts lgkm wait for frag deps before first MFMA
    MM16(afA, bfA);
    MM16(afB, bfB);
    if (k < NT / 2 - 1) {
      const int t = 2 * k;
      asm volatile("s_waitcnt lgkmcnt(0)" ::: "memory");
      asm volatile("s_waitcnt vmcnt(0)" ::: "memory");
      SBAR();
      if (t + 4 < NT) stage(t + 4);
      if (t + 5 < NT) stage(t + 5);
      readfr(t + 2, afA, bfA);
      readfr(t + 3, afB, bfB);
    }
  }
#undef MM16

  // epilogue: relu(acc+bias), weighted column reduce, atomic accumulate
  int ncol[4];
  float bsv[4];
#pragma unroll
  for (int ni = 0; ni < 4; ++ni) {
    ncol[ni] = n0 + wc * 64 + ni * 16 + r15;  // C/D: col = lane&15
    bsv[ni] = bias[ncol[ni]];
  }
#pragma unroll
  for (int mi = 0; mi < 4; ++mi)
#pragma unroll
    for (int ni = 0; ni < 4; ++ni)
#pragma unroll
      for (int j = 0; j < 4; ++j) {
        float v = acc[mi][ni][j] + bsv[ni];
        acc[mi][ni][j] = v > 0.f ? v : 0.f;
      }
#pragma unroll
  for (int jo = 0; jo < NJO; ++jo) {
    float w4[4];
#pragma unroll
    for (int ni = 0; ni < 4; ++ni)
      w4[ni] = (NJO == 1) ? W2[ncol[ni]] : W2[ncol[ni] * NJO + jo];
#pragma unroll
    for (int mi = 0; mi < 4; ++mi)
#pragma unroll
      for (int j = 0; j < 4; ++j) {
        float s2 = acc[mi][0][j] * w4[0] + acc[mi][1][j] * w4[1] +
                   acc[mi][2][j] * w4[2] + acc[mi][3][j] * w4[3];
        s2 += __shfl_xor(s2, 1);
        s2 += __shfl_xor(s2, 2);
        s2 += __shfl_xor(s2, 4);
        s2 += __shfl_xor(s2, 8);
        if (r15 == 0) {
          const int row = m0 + wr * 64 + mi * 16 + g4 * 4 + j;  // C/D: row=(lane>>4)*4+reg
          const int oc = (NJO == 1) ? (n0 >> 10) : jo;
          atomicAdd(&out[row * KEXP + oc], s2);
        }
      }
  }
}

// ---------------- entmax (alpha=1.5, 50 bisect iters) + combine + gate colsums ------------
__global__ void entmax_combine(const float* __restrict__ gacc, const float* __restrict__ gb2,
                               const float* __restrict__ yk, const float* __restrict__ eb2,
                               float* __restrict__ y, double* __restrict__ colsum) {
  const int b = blockIdx.x * 256 + threadIdx.x;
  float x[16];
  float mx = -3.4e38f;
#pragma unroll
  for (int j = 0; j < 16; ++j) {
    x[j] = (gacc[b * 16 + j] + gb2[j]) * 0.5f;  // * (alpha-1)
    mx = fmaxf(mx, x[j]);
  }
  float lo = mx - 1.0f, hi = mx - 0.25f;  // d^(1-alpha) = 16^-0.5
  float flo = -1.0f;
#pragma unroll
  for (int j = 0; j < 16; ++j) {
    float d = x[j] - lo; d = d > 0.f ? d : 0.f;
    flo += d * d;
  }
  for (int it = 0; it < 50; ++it) {
    const float tm = 0.5f * (lo + hi);
    float fm = -1.0f;
#pragma unroll
    for (int j = 0; j < 16; ++j) {
      float d = x[j] - tm; d = d > 0.f ? d : 0.f;
      fm += d * d;
    }
    if (fm * flo >= 0.f) { lo = tm; flo = fm; } else { hi = tm; }
  }
  const float tm = 0.5f * (lo + hi);
  float p[16], ps = 0.f;
#pragma unroll
  for (int j = 0; j < 16; ++j) {
    float d = x[j] - tm; d = d > 0.f ? d : 0.f;
    p[j] = d * d; ps += p[j];
  }
  const float inv = 1.0f / ps;
  float yv = 0.f;
#pragma unroll
  for (int j = 0; j < 16; ++j) {
    p[j] *= inv;
    yv += p[j] * (yk[b * 16 + j] + eb2[j]);
  }
  y[b] = yv;

  const int lane = threadIdx.x & 63, wv = threadIdx.x >> 6;
  __shared__ float red[4][16];
#pragma unroll
  for (int j = 0; j < 16; ++j) {
    float v = p[j];
    v += __shfl_xor(v, 1);  v += __shfl_xor(v, 2);  v += __shfl_xor(v, 4);
    v += __shfl_xor(v, 8);  v += __shfl_xor(v, 16); v += __shfl_xor(v, 32);
    if (lane == 0) red[wv][j] = v;
  }
  __syncthreads();
  if (threadIdx.x < 16) {
    double s = (double)red[0][threadIdx.x] + (double)red[1][threadIdx.x] +
               (double)red[2][threadIdx.x] + (double)red[3][threadIdx.x];
    atomicAdd(&colsum[threadIdx.x], s);
  }
}

__global__ void loss_k(const double* __restrict__ colsum, float* __restrict__ out) {
  if (threadIdx.x == 0 && blockIdx.x == 0) {
    double m = 0.0;
    for (int k = 0; k < 16; ++k) m += colsum[k];
    m *= (1.0 / 16.0);
    double var = 0.0;
    for (int k = 0; k < 16; ++k) { const double d = colsum[k] - m; var += d * d; }
    var *= (1.0 / 15.0);  // ddof=1
    out[0] = (float)(var / (m * m + 1e-10));
  }
}

// ---------------- launch ----------------
extern "C" void kernel_launch(void* const* d_in, const int* in_sizes, int n_in,
                              void* d_out, int out_size, void* d_ws, size_t ws_size,
                              hipStream_t stream) {
  const int*   x    = (const int*)d_in[0];
  const int*   sql  = (const int*)d_in[1];
  const float* sqlT = (const float*)d_in[2];
  const float* inT  = (const float*)d_in[3];
  const float* gW1  = (const float*)d_in[4];
  const float* gb1  = (const float*)d_in[5];
  const float* gW2  = (const float*)d_in[6];
  const float* gb2  = (const float*)d_in[7];
  const float* eW1  = (const float*)d_in[8];
  const float* eb1  = (const float*)d_in[9];
  const float* eW2  = (const float*)d_in[10];
  const float* eb2  = (const float*)d_in[11];

  char* ws = (char*)d_ws;
  unsigned short* eW1T = (unsigned short*)(ws);              // [16384][1280] bf16
  unsigned short* xemb = (unsigned short*)(ws + 41943040);   // [8192][1280]
  unsigned short* semb = (unsigned short*)(ws + 62914560);   // [8192][320]
  unsigned short* gW1T = (unsigned short*)(ws + 68157440);   // [1024][320]
  float*  yk     = (float*)(ws + 68812800);                  // [8192][16]
  float*  gacc   = (float*)(ws + 69337088);                  // [8192][16]
  double* colsum = (double*)(ws + 69861376);                 // [16]

  hipMemsetAsync(yk, 0, 524288 * 2 + 128, stream);

  transpose_cvt<<<dim3(32, 40, 16), 256, 0, stream>>>(eW1, eW1T, 1280, 1024, 1280L * 1024, 1024L * 1280);
  transpose_cvt<<<dim3(32, 10, 1), 256, 0, stream>>>(gW1, gW1T, 320, 1024, 0, 0);
  gather_x_k<<<BATCH, 320, 0, stream>>>(x, inT, xemb);
  gather_sql_k<<<BATCH * 80 / 256, 256, 0, stream>>>(sql, sqlT, semb);

  gemm_q<1, KX><<<dim3(16384 / 128, BATCH / 128), 256, 0, stream>>>(
      (const __bf16*)xemb, (const __bf16*)eW1T, eb1, eW2, yk);
  gemm_q<16, KS><<<dim3(HID / 128, BATCH / 128), 256, 0, stream>>>(
      (const __bf16*)semb, (const __bf16*)gW1T, gb1, gW2, gacc);

  entmax_combine<<<BATCH / 256, 256, 0, stream>>>(gacc, gb2, yk, eb2, (float*)d_out, colsum);
  loss_k<<<1, 64, 0, stream>>>(colsum, (float*)d_out + BATCH);
}